// Round 17
// baseline (51.625 us; speedup 1.0000x reference)
//
#include <hip/hip_runtime.h>

// Problem constants (match reference setup)
#define BB     4
#define NW     128
#define HG     512
#define WG     512
#define EDIM   64
#define HIDDEN 768

typedef float f4 __attribute__((ext_vector_type(4)));

// ---------------------------------------------------------------------------
// Single fused kernel — R16 + hoisted full-cover GATHER (not just winner).
// 2048 blocks = 8 XCDs x 256; lin = b(2)|e4(4)|ht(5); 4 e-planes per block,
// 16-row tile, wave = one 4-row window. Plain f4 stores (NT hurts: R8).
//
// Phase 1 : filter this batch's 128 boxes against rows [ht*16, ht*16+16).
// Phase 1b: per 4-row window, split FULL (covers all 4 rows) vs PARTIAL.
// Phase 2 : wave-parallel 768-dots for 4 planes.
// Phase 3 : hoist full-box winner AND its gathered values hu[] per window;
//           pmask = rows touched by partial boxes. Clear rows: 8 stores only.
// ---------------------------------------------------------------------------
__global__ __launch_bounds__(256) void fused_kernel(
    const float* __restrict__ bbox,
    const float* __restrict__ emb,
    const float* __restrict__ proj,
    const int*   __restrict__ ids,
    const int*   __restrict__ stride_p,
    float*       __restrict__ out)
{
    const int t = threadIdx.x;
    // 2048 = 8 XCDs x 256; block i -> XCD i%8 -> contiguous lin chunk.
    const int lin = ((blockIdx.x & 7) << 8) | (blockIdx.x >> 3);
    const int b  = lin >> 9;             // 2 XCDs per batch
    const int e0 = ((lin >> 5) & 15) * 4;
    const int ht = lin & 31;
    const int rlo = ht * 16, rhi = rlo + 16;

    __shared__ unsigned entx[NW];        // w0 | w1<<10 | prio<<20
    __shared__ unsigned enty[NW];        // h0 | h1<<16
    __shared__ int      sid[NW];         // word id per filtered box
    __shared__ float    col[4][NW + 1];  // per-plane values by prio (0=bg)
    __shared__ unsigned char subF[4][NW];  // full-cover boxes per 4-row window
    __shared__ unsigned char subP[4][NW];  // partial-cover boxes
    __shared__ int      cntF[4], cntP[4];
    __shared__ int      cnt;

    if (t == 0) cnt = 0;
    if (t < 4)  { cntF[t] = 0; cntP[t] = 0; }
    __syncthreads();

    // ---- Phase 1: box filter for this 16-row tile ----
    if (t < NW) {
        const float s = (float)stride_p[0];
        float4 bv = ((const float4*)bbox)[b * NW + t];
        int w0 = (int)rintf(bv.x / s), h0 = (int)rintf(bv.y / s);
        int w1 = (int)rintf(bv.z / s), h1 = (int)rintf(bv.w / s);
        if (h1 > rlo && h0 < rhi && w1 > w0 && h1 > h0) {
            int i = atomicAdd(&cnt, 1);
            entx[i] = (unsigned)w0 | ((unsigned)w1 << 10) | ((unsigned)(t + 1) << 20);
            enty[i] = (unsigned)h0 | ((unsigned)h1 << 16);
            sid[i]  = ids[b * NW + t];
        }
    }
    __syncthreads();

    const int nc = cnt;
    const int wv = t >> 6, l = t & 63;

    // ---- Phase 1b: full/partial split per 4-row window ----
    if (t < nc) {
        const unsigned ey = enty[t];
        const int h0 = (int)(ey & 0xFFFFu), h1 = (int)(ey >> 16);
        #pragma unroll
        for (int wi = 0; wi < 4; ++wi) {
            const int wr = rlo + wi * 4;
            if (h0 <= wr && h1 >= wr + 4) {              // covers all 4 rows
                int k = atomicAdd(&cntF[wi], 1);
                subF[wi][k] = (unsigned char)t;
            } else if (h1 > wr && h0 < wr + 4) {         // partial overlap
                int k = atomicAdd(&cntP[wi], 1);
                subP[wi][k] = (unsigned char)t;
            }
        }
    }

    // ---- Phase 2: table entries for 4 planes (j == nc -> background) ----
    for (int j = wv; j <= nc; j += 4) {
        const int id   = (j == nc) ? 0 : sid[j];
        const int slot = (j == nc) ? 0 : (int)(entx[j] >> 20);
        const f4* er = (const f4*)(emb + (size_t)id * HIDDEN) + l * 3;
        f4 a0 = er[0], a1 = er[1], a2 = er[2];
        float v[4];
        #pragma unroll
        for (int p = 0; p < 4; ++p) {
            const f4* pr = (const f4*)(proj + (size_t)(e0 + p) * HIDDEN) + l * 3;
            f4 p0 = pr[0], p1 = pr[1], p2 = pr[2];
            v[p] = a0.x*p0.x + a0.y*p0.y + a0.z*p0.z + a0.w*p0.w
                 + a1.x*p1.x + a1.y*p1.y + a1.z*p1.z + a1.w*p1.w
                 + a2.x*p2.x + a2.y*p2.y + a2.z*p2.z + a2.w*p2.w;
        }
        #pragma unroll
        for (int m = 1; m < 64; m <<= 1) {
            v[0] += __shfl_xor(v[0], m, 64);
            v[1] += __shfl_xor(v[1], m, 64);
            v[2] += __shfl_xor(v[2], m, 64);
            v[3] += __shfl_xor(v[3], m, 64);
        }
        if (l == 0) {
            col[0][slot] = v[0]; col[1][slot] = v[1];
            col[2][slot] = v[2]; col[3][slot] = v[3];
        }
    }
    __syncthreads();

    // ---- Phase 3: 4 rows per wave; hoisted winner AND gather ----
    const int wrlo = rlo + wv * 4;
    const int nF = cntF[wv], nP = cntP[wv];
    const int p0i = 4 * l, p1i = 256 + 4 * l;
    float* ob = out + ((size_t)(b * EDIM + e0)) * HG * WG;
    const size_t PLq = (size_t)HG * WG / 4;            // plane stride in f4

    // row-invariant winner from full-cover boxes (no row test)
    int f0 = 0, f1 = 0, f2 = 0, f3 = 0, f4_ = 0, f5 = 0, f6 = 0, f7 = 0;
    for (int k = 0; k < nF; ++k) {
        const unsigned ex = entx[subF[wv][k]];
        const int w0 = (int)(ex & 1023u);
        const int w1 = (int)((ex >> 10) & 1023u);
        const int pr = (int)(ex >> 20);
        if (p0i     >= w0 && p0i     < w1 && pr > f0)  f0  = pr;
        if (p0i + 1 >= w0 && p0i + 1 < w1 && pr > f1)  f1  = pr;
        if (p0i + 2 >= w0 && p0i + 2 < w1 && pr > f2)  f2  = pr;
        if (p0i + 3 >= w0 && p0i + 3 < w1 && pr > f3)  f3  = pr;
        if (p1i     >= w0 && p1i     < w1 && pr > f4_) f4_ = pr;
        if (p1i + 1 >= w0 && p1i + 1 < w1 && pr > f5)  f5  = pr;
        if (p1i + 2 >= w0 && p1i + 2 < w1 && pr > f6)  f6  = pr;
        if (p1i + 3 >= w0 && p1i + 3 < w1 && pr > f7)  f7  = pr;
    }

    // hoisted gather for the row-invariant winner (subsumes bg case)
    f4 hu0[4], hu1[4];
    #pragma unroll
    for (int p = 0; p < 4; ++p) {
        hu0[p].x = col[p][f0];  hu0[p].y = col[p][f1];
        hu0[p].z = col[p][f2];  hu0[p].w = col[p][f3];
        hu1[p].x = col[p][f4_]; hu1[p].y = col[p][f5];
        hu1[p].z = col[p][f6];  hu1[p].w = col[p][f7];
    }

    // rows touched by partial boxes (wave-uniform 4-bit mask)
    unsigned pmask = 0;
    for (int k = 0; k < nP; ++k) {
        const unsigned ey = enty[subP[wv][k]];
        const int h0 = (int)(ey & 0xFFFFu), h1 = (int)(ey >> 16);
        const int lo = max(h0 - wrlo, 0), hi = min(h1 - wrlo, 4);
        pmask |= ((1u << hi) - 1u) & ~((1u << lo) - 1u);
    }

    for (int rr = 0; rr < 4; ++rr) {
        const int row = wrlo + rr;                     // wave-uniform
        f4* orow = (f4*)(ob + (size_t)row * WG);

        if (!((pmask >> rr) & 1u)) {                   // hoisted fast path
            #pragma unroll
            for (int p = 0; p < 4; ++p) {
                f4* op = orow + p * PLq;
                op[l]      = hu0[p];
                op[64 + l] = hu1[p];
            }
            continue;
        }

        int wn0 = f0, wn1 = f1, wn2 = f2, wn3 = f3;
        int wn4 = f4_, wn5 = f5, wn6 = f6, wn7 = f7;
        for (int k = 0; k < nP; ++k) {
            const int i = subP[wv][k];
            const unsigned ey = enty[i];               // broadcast LDS read
            const int h0 = (int)(ey & 0xFFFFu), h1 = (int)(ey >> 16);
            if (row >= h0 && row < h1) {               // wave-uniform branch
                const unsigned ex = entx[i];
                const int w0 = (int)(ex & 1023u);
                const int w1 = (int)((ex >> 10) & 1023u);
                const int pr = (int)(ex >> 20);
                if (p0i     >= w0 && p0i     < w1 && pr > wn0) wn0 = pr;
                if (p0i + 1 >= w0 && p0i + 1 < w1 && pr > wn1) wn1 = pr;
                if (p0i + 2 >= w0 && p0i + 2 < w1 && pr > wn2) wn2 = pr;
                if (p0i + 3 >= w0 && p0i + 3 < w1 && pr > wn3) wn3 = pr;
                if (p1i     >= w0 && p1i     < w1 && pr > wn4) wn4 = pr;
                if (p1i + 1 >= w0 && p1i + 1 < w1 && pr > wn5) wn5 = pr;
                if (p1i + 2 >= w0 && p1i + 2 < w1 && pr > wn6) wn6 = pr;
                if (p1i + 3 >= w0 && p1i + 3 < w1 && pr > wn7) wn7 = pr;
            }
        }
        #pragma unroll
        for (int p = 0; p < 4; ++p) {
            f4 u0, u1;
            u0.x = col[p][wn0]; u0.y = col[p][wn1];
            u0.z = col[p][wn2]; u0.w = col[p][wn3];
            u1.x = col[p][wn4]; u1.y = col[p][wn5];
            u1.z = col[p][wn6]; u1.w = col[p][wn7];
            f4* op = orow + p * PLq;
            op[l]      = u0;
            op[64 + l] = u1;
        }
    }
}

// ---------------------------------------------------------------------------
extern "C" void kernel_launch(void* const* d_in, const int* in_sizes, int n_in,
                              void* d_out, int out_size, void* d_ws, size_t ws_size,
                              hipStream_t stream)
{
    // inputs: 0 img (unused), 1 bbox, 2 emb_weight, 3 proj_weight,
    //         4 input_ids, 5 stride
    const float* bbox = (const float*)d_in[1];
    const float* emb  = (const float*)d_in[2];
    const float* proj = (const float*)d_in[3];
    const int*   ids  = (const int*)d_in[4];
    const int*   strd = (const int*)d_in[5];

    float* out = (float*)d_out;

    fused_kernel<<<2048, 256, 0, stream>>>(bbox, emb, proj, ids, strd, out);
}